// Round 6
// baseline (729.386 us; speedup 1.0000x reference)
//
#include <hip/hip_runtime.h>

// XTAttention — ROUND 9: round-8 2-phase dbuf pipeline, compile-fixed.
// r8 failed to compile: local array of LDS pointers => unsupported
// addrspacecast static initializer. Replaced with computed-offset macros.
// Design unchanged: BK=32 dbuf LDS (2x16KB=32KB), STAGE(t+1) issued into
// the other buffer BEFORE computing tile t, single __syncthreads() per
// K-step AFTER the MFMAs. BK=32 bank swizzle: granule ^= (row>>1)&3.
// Epilogues (r7 coalesced LDS-stage) kept. attn/casts unchanged.
// B=128,N=128,D=1024,H=8,HD=128.

typedef unsigned short u16;
typedef __attribute__((ext_vector_type(8))) short bf16x8;  // 8 bf16, 4 VGPR
typedef __attribute__((ext_vector_type(4))) short bf16x4;  // 4 bf16, 2 VGPR
typedef __attribute__((ext_vector_type(4))) float f32x4;

__device__ __forceinline__ float bf2f(u16 x) {
  union { unsigned u; float f; } v;
  v.u = ((unsigned)x) << 16;
  return v.f;
}

__device__ __forceinline__ u16 f2bf(float f) {
  union { float f; unsigned u; } v;
  v.f = f;
  unsigned r = v.u + 0x7fffu + ((v.u >> 16) & 1u);  // RTNE
  return (u16)(r >> 16);
}

__device__ __forceinline__ float ldv(const void* p, size_t i, int f32) {
  return f32 ? ((const float*)p)[i] : bf2f(((const u16*)p)[i]);
}

__device__ __forceinline__ f32x4 MFMA(bf16x8 a, bf16x8 b, f32x4 c) {
  return __builtin_amdgcn_mfma_f32_16x16x32_bf16(a, b, c, 0, 0, 0);
}

#define GLDS16(gp, lp)                                               \
  __builtin_amdgcn_global_load_lds(                                  \
      (const __attribute__((address_space(1))) unsigned int*)(gp),   \
      (__attribute__((address_space(3))) unsigned int*)(lp), 16, 0, 0)

// BK=32 swizzled frag read: [128][32] bf16 tile, 64B rows. Stored granule
// g holds source granule g ^ ((row>>1)&3)  => reading granule fq^s yields fq.
__device__ __forceinline__ bf16x8 lds_frag32(const u16* ls, int row, int fq) {
  const int byte = row * 64 + ((fq ^ ((row >> 1) & 3)) << 4);
  return *(const bf16x8*)((const char*)ls + byte);
}

// C-stage swizzle for a [128][128] bf16 tile (256B rows): bijective within
// row (XOR touches only col bits 4..6).
__device__ __forceinline__ int cs_byte(int row, int colb) {
  return (row * 256 + colb) ^ ((row & 7) << 4);
}

// ---------------------------------------------------------------------------
// Dtype detection (inputs proved f32 in round 3; keep runtime check).
// ---------------------------------------------------------------------------
__global__ void detect_dtype(const void* words, int* flag) {
  __shared__ int cnt;
  if (threadIdx.x == 0) cnt = 0;
  __syncthreads();
  const u16* w = (const u16*)words;
  int local = 0;
  for (int i = threadIdx.x; i < 2048; i += 256) {
    const u16 v = w[2 * i];
    const int e = (v >> 7) & 0xFF;
    if (v == 0 || (e >= 0x60 && e <= 0x8F)) local++;
  }
  atomicAdd(&cnt, local);
  __syncthreads();
  if (threadIdx.x == 0) *flag = (cnt >= 1434) ? 0 : 1;  // 1 = f32
}

// ---------------------------------------------------------------------------
// Cast + transpose the 8 weight matrices: WT[p][n][k] = W[p][k][n], bf16.
// ---------------------------------------------------------------------------
__global__ __launch_bounds__(256) void cast_w(
    const void* w0, const void* w1, const void* w2, const void* w3,
    const void* w4, const void* w5, const void* w6, const void* w7,
    u16* __restrict__ WT, const int* __restrict__ flag) {
  __shared__ float t[32][33];
  const int f32 = *flag;
  const int p = blockIdx.z;
  const void* W;
  switch (p) {
    case 0: W = w0; break; case 1: W = w1; break; case 2: W = w2; break;
    case 3: W = w3; break; case 4: W = w4; break; case 5: W = w5; break;
    case 6: W = w6; break; default: W = w7; break;
  }
  const int k0 = blockIdx.y * 32, n0 = blockIdx.x * 32;
  const int tx = threadIdx.x & 31, ry = threadIdx.x >> 5;
  for (int r = ry; r < 32; r += 8)
    t[r][tx] = ldv(W, (size_t)(k0 + r) * 1024 + n0 + tx, f32);
  __syncthreads();
  u16* dst = WT + (size_t)p * 1048576ull;
  for (int r = ry; r < 32; r += 8)
    dst[(size_t)(n0 + r) * 1024 + k0 + tx] = f2bf(t[tx][r]);
}

// ---------------------------------------------------------------------------
// Cast activations (chunk rows) to bf16. grid (512,1,3).
// ---------------------------------------------------------------------------
__global__ __launch_bounds__(256) void cast_a(
    const void* x0, const void* x1, const void* x2, u16* __restrict__ Abf,
    int b0, int chb, const int* __restrict__ flag) {
  const int f32 = *flag;
  const int t = blockIdx.z;
  const void* src = (t == 0) ? x0 : ((t == 1) ? x1 : x2);
  u16* dst = Abf + (size_t)t * (size_t)chb * 131072ull;
  const size_t n4 = (size_t)chb * 32768ull;
  const size_t off = (size_t)b0 * 131072ull;
  const size_t stride = (size_t)gridDim.x * 256ull;
  if (f32) {
    const float4* s = (const float4*)src + off / 4;
    for (size_t i = (size_t)blockIdx.x * 256 + threadIdx.x; i < n4; i += stride) {
      const float4 v = s[i];
      bf16x4 o = { (short)f2bf(v.x), (short)f2bf(v.y),
                   (short)f2bf(v.z), (short)f2bf(v.w) };
      *(bf16x4*)&dst[i * 4] = o;
    }
  } else {
    const bf16x4* s = (const bf16x4*)((const u16*)src + off);
    for (size_t i = (size_t)blockIdx.x * 256 + threadIdx.x; i < n4; i += stride)
      ((bf16x4*)dst)[i] = s[i];
  }
}

// ---------------------------------------------------------------------------
// 7 projections, MFMA. 128x128 tile/block, 4 waves (2x2), BK=32, 2-phase
// double-buffered. Epilogue: LDS-stage + 16B/lane coalesced stores.
// Streams 1,2,4,6 stored per-head transposed: T[(b*8+h)*128 + d][j].
// ---------------------------------------------------------------------------
__global__ __launch_bounds__(256) void proj_mfma(
    const u16* __restrict__ Abf, const u16* __restrict__ WT,
    u16* __restrict__ P, int chb) {
  __shared__ u16 lds[16384];  // 32KB: K-loop = 2x(A 8KB + B 8KB); epi = C-stage
#define LA(buf) (lds + (buf) * 4096)
#define LB(buf) (lds + 8192 + (buf) * 4096)
  const int p = blockIdx.z;
  const int asel = (p < 3) ? 0 : ((p < 5) ? 1 : 2);
  const u16* A = Abf + (size_t)asel * (size_t)chb * 131072ull;
  const u16* W = WT + (size_t)p * 1048576ull;
  u16* C = P + (size_t)p * (size_t)chb * 131072ull;
  const int tr = (p == 1) | (p == 2) | (p == 4) | (p == 6);

  // XCD-aware bijective remap (nwg = 8*CHB, divisible by 8).
  int wg = blockIdx.y * 8 + blockIdx.x;
  const int nwg = (int)gridDim.y * 8;
  wg = (wg & 7) * (nwg >> 3) + (wg >> 3);
  const int bx = wg & 7, by = wg >> 3;

  const int tn = bx * 128;
  const int tm = by * 128;
  const int w = threadIdx.x >> 6, l = threadIdx.x & 63;
  const int wm = w >> 1, wn = w & 1;
  const int fr = l & 15, fq = l >> 4;  // fragment row / k-granule

  // Staging (BK=32): lane covers row (l>>2) within a 16-row slab, granule
  // (l&3); source granule pre-XOR'd by s(row) = ((l>>2)>>1)&3 = (l>>3)&3.
  const int srow = l >> 2;                          // 0..15
  const int sgr = (l & 3) ^ ((l >> 3) & 3);         // pre-swizzled granule
  const unsigned abase = (unsigned)(tm + w * 32 + srow) * 1024u + sgr * 8u;
  const unsigned bbase = (unsigned)(tn + w * 32 + srow) * 1024u + sgr * 8u;
  const int ldst0 = (w * 32) * 32;                  // u16 index of slab 0
  const int ldst1 = (w * 32 + 16) * 32;             // u16 index of slab 1

#define STAGE(buf, kt)                                           \
  {                                                              \
    GLDS16(&A[abase + (unsigned)(kt)], &LA(buf)[ldst0]);         \
    GLDS16(&A[abase + 16384u + (unsigned)(kt)], &LA(buf)[ldst1]);\
    GLDS16(&W[bbase + (unsigned)(kt)], &LB(buf)[ldst0]);         \
    GLDS16(&W[bbase + 16384u + (unsigned)(kt)], &LB(buf)[ldst1]);\
  }

  f32x4 acc[4][4] = {};
  STAGE(0, 0);
  __syncthreads();  // drains prologue loads

  for (int t = 0; t < 32; ++t) {
    const int cur = t & 1;
    if (t < 31) STAGE(cur ^ 1, (t + 1) * 32);  // async into other buffer
    bf16x8 af[4], bfr[4];
    #pragma unroll
    for (int m = 0; m < 4; ++m)
      af[m] = lds_frag32(LA(cur), wm * 64 + m * 16 + fr, fq);
    #pragma unroll
    for (int n = 0; n < 4; ++n)
      bfr[n] = lds_frag32(LB(cur), wn * 64 + n * 16 + fr, fq);
    #pragma unroll
    for (int m = 0; m < 4; ++m)
      #pragma unroll
      for (int n = 0; n < 4; ++n)
        acc[m][n] = MFMA(af[m], bfr[n], acc[m][n]);
    __syncthreads();  // drains this iter's STAGE; next iter reads it
  }
#undef STAGE
#undef LA
#undef LB

  // ---- epilogue: stage C tile (transposed for tr streams), coalesced out
  #pragma unroll
  for (int m = 0; m < 4; ++m)
    #pragma unroll
    for (int n = 0; n < 4; ++n)
      #pragma unroll
      for (int r = 0; r < 4; ++r) {
        const int row = wm * 64 + m * 16 + fq * 4 + r;   // local out row
        const int col = wn * 64 + n * 16 + fr;           // local out col
        const int sr = tr ? col : row;                   // staged row
        const int sc = tr ? row : col;                   // staged col
        *(u16*)((char*)lds + cs_byte(sr, sc * 2)) = f2bf(acc[m][n][r]);
      }
  __syncthreads();
  const int crow = threadIdx.x >> 4;            // 0..15
  const int ccb = (threadIdx.x & 15) * 16;      // byte col 0..240
  if (!tr) {
    #pragma unroll
    for (int pass = 0; pass < 8; ++pass) {
      const int row = pass * 16 + crow;
      const bf16x8 v = *(const bf16x8*)((const char*)lds + cs_byte(row, ccb));
      *(bf16x8*)&C[(size_t)(tm + row) * 1024 + tn + (ccb >> 1)] = v;
    }
  } else {
    const size_t tb = ((size_t)by * 8 + bx) * 16384ull;  // (b,h) tile base
    #pragma unroll
    for (int pass = 0; pass < 8; ++pass) {
      const int d = pass * 16 + crow;
      const bf16x8 v = *(const bf16x8*)((const char*)lds + cs_byte(d, ccb));
      *(bf16x8*)&C[tb + (size_t)d * 128 + (ccb >> 1)] = v;
    }
  }
}

// ---------------------------------------------------------------------------
// Attention: one block per (b_local, h), 4 waves x 32 rows. (Unchanged r7.)
// ---------------------------------------------------------------------------
__global__ __launch_bounds__(256) void attn_mfma(
    const u16* __restrict__ P, int chb, u16* __restrict__ merged) {
  __shared__ u16 pl[16384];  // 128x128 bf16, row-swizzled
  const int h = blockIdx.x, b = blockIdx.y;
  const int w = threadIdx.x >> 6, l = threadIdx.x & 63;
  const size_t MS = (size_t)chb * 131072ull;
  const u16* const Qs[3] = { P, P + 3 * MS, P + 5 * MS };
  const u16* const Ks[3] = { P + 1 * MS, P + 4 * MS, P + 6 * MS };
  const u16* V = P + 2 * MS;
  const size_t qb = (size_t)b * 131072ull + (size_t)h * 128;
  const size_t kb = ((size_t)b * 8 + h) * 16384ull;

  f32x4 acc[2][8] = {};
  #pragma unroll
  for (int kt = 0; kt < 128; kt += 32) {
    #pragma unroll
    for (int t = 0; t < 3; ++t) {
      bf16x8 a[2];
      #pragma unroll
      for (int m = 0; m < 2; ++m)
        a[m] = *(const bf16x8*)&Qs[t][qb + (size_t)(w * 32 + m * 16 + (l & 15)) * 1024
                                       + kt + (l >> 4) * 8];
      #pragma unroll
      for (int n = 0; n < 8; ++n) {
        const bf16x8 bb = *(const bf16x8*)&Ks[t][kb + (size_t)(n * 16 + (l & 15)) * 128
                                                 + kt + (l >> 4) * 8];
        acc[0][n] = MFMA(a[0], bb, acc[0][n]);
        acc[1][n] = MFMA(a[1], bb, acc[1][n]);
      }
    }
  }

  const float SC = 0.08838834764831845f;
  #pragma unroll
  for (int m = 0; m < 2; ++m)
    #pragma unroll
    for (int r = 0; r < 4; ++r) {
      float mx = -3.0e38f;
      #pragma unroll
      for (int n = 0; n < 8; ++n) {
        acc[m][n][r] *= SC;
        mx = fmaxf(mx, acc[m][n][r]);
      }
      #pragma unroll
      for (int s = 1; s < 16; s <<= 1) mx = fmaxf(mx, __shfl_xor(mx, s));
      float sm = 0.f;
      #pragma unroll
      for (int n = 0; n < 8; ++n) {
        const float e = __expf(acc[m][n][r] - mx);
        acc[m][n][r] = e;
        sm += e;
      }
      #pragma unroll
      for (int s = 1; s < 16; s <<= 1) sm += __shfl_xor(sm, s);
      const float inv = 1.f / sm;
      #pragma unroll
      for (int n = 0; n < 8; ++n) acc[m][n][r] *= inv;
    }

  #pragma unroll
  for (int m = 0; m < 2; ++m)
    #pragma unroll
    for (int n = 0; n < 8; ++n)
      #pragma unroll
      for (int r = 0; r < 4; ++r) {
        const int row = w * 32 + m * 16 + (l >> 4) * 4 + r;
        const int col = n * 16 + (l & 15);
        const int byte = (row * 256 + col * 2) ^ ((row & 7) << 4);
        *(u16*)((char*)pl + byte) = f2bf(acc[m][n][r]);
      }
  __syncthreads();

  f32x4 o[2][8] = {};
  #pragma unroll
  for (int kt = 0; kt < 128; kt += 32) {
    bf16x8 a[2];
    #pragma unroll
    for (int m = 0; m < 2; ++m) {
      const int row = w * 32 + m * 16 + (l & 15);
      const int byte = (row * 256 + (kt + (l >> 4) * 8) * 2) ^ ((row & 7) << 4);
      a[m] = *(const bf16x8*)((char*)pl + byte);
    }
    #pragma unroll
    for (int n = 0; n < 8; ++n) {
      const bf16x8 bb = *(const bf16x8*)&V[kb + (size_t)(n * 16 + (l & 15)) * 128
                                           + kt + (l >> 4) * 8];
      o[0][n] = MFMA(a[0], bb, o[0][n]);
      o[1][n] = MFMA(a[1], bb, o[1][n]);
    }
  }

  // ---- merged write: stage into pl (all waves done reading), coalesce out
  __syncthreads();
  #pragma unroll
  for (int m = 0; m < 2; ++m)
    #pragma unroll
    for (int n = 0; n < 8; ++n)
      #pragma unroll
      for (int r = 0; r < 4; ++r) {
        const int row = w * 32 + m * 16 + (l >> 4) * 4 + r;
        const int col = n * 16 + (l & 15);
        *(u16*)((char*)pl + cs_byte(row, col * 2)) = f2bf(o[m][n][r]);
      }
  __syncthreads();
  const int crow = threadIdx.x >> 4;
  const int ccb = (threadIdx.x & 15) * 16;
  #pragma unroll
  for (int pass = 0; pass < 8; ++pass) {
    const int row = pass * 16 + crow;
    const bf16x8 v = *(const bf16x8*)((const char*)pl + cs_byte(row, ccb));
    *(bf16x8*)&merged[(size_t)(b * 128 + row) * 1024 + h * 128 + (ccb >> 1)] = v;
  }
}

// ---------------------------------------------------------------------------
// Final projection: out = merged @ Wo + bo. BK=32 2-phase dbuf K-loop;
// output staged through LDS in two 32KB f32 half-passes (r7 epilogue).
// ---------------------------------------------------------------------------
__global__ __launch_bounds__(256) void final_mfma(
    const u16* __restrict__ A, const u16* __restrict__ W,
    const void* __restrict__ bias, void* __restrict__ out, int b0,
    const int* __restrict__ flag) {
  __shared__ u16 lds[16384];  // 32KB: K-loop = 2x(A+B); epilogue = f32 stage
#define LA(buf) (lds + (buf) * 4096)
#define LB(buf) (lds + 8192 + (buf) * 4096)
  const int f32 = *flag;

  int wg = blockIdx.y * 8 + blockIdx.x;
  const int nwg = (int)gridDim.y * 8;
  wg = (wg & 7) * (nwg >> 3) + (wg >> 3);
  const int bx = wg & 7, by = wg >> 3;

  const int tn = bx * 128;
  const int tm = by * 128;
  const int w = threadIdx.x >> 6, l = threadIdx.x & 63;
  const int wm = w >> 1, wn = w & 1;
  const int fr = l & 15, fq = l >> 4;

  const int srow = l >> 2;
  const int sgr = (l & 3) ^ ((l >> 3) & 3);
  const unsigned abase = (unsigned)(tm + w * 32 + srow) * 1024u + sgr * 8u;
  const unsigned bbase = (unsigned)(tn + w * 32 + srow) * 1024u + sgr * 8u;
  const int ldst0 = (w * 32) * 32;
  const int ldst1 = (w * 32 + 16) * 32;

#define STAGE(buf, kt)                                           \
  {                                                              \
    GLDS16(&A[abase + (unsigned)(kt)], &LA(buf)[ldst0]);         \
    GLDS16(&A[abase + 16384u + (unsigned)(kt)], &LA(buf)[ldst1]);\
    GLDS16(&W[bbase + (unsigned)(kt)], &LB(buf)[ldst0]);         \
    GLDS16(&W[bbase + 16384u + (unsigned)(kt)], &LB(buf)[ldst1]);\
  }

  f32x4 acc[4][4] = {};
  STAGE(0, 0);
  __syncthreads();

  for (int t = 0; t < 32; ++t) {
    const int cur = t & 1;
    if (t < 31) STAGE(cur ^ 1, (t + 1) * 32);
    bf16x8 af[4], bfr[4];
    #pragma unroll
    for (int m = 0; m < 4; ++m)
      af[m] = lds_frag32(LA(cur), wm * 64 + m * 16 + fr, fq);
    #pragma unroll
    for (int n = 0; n < 4; ++n)
      bfr[n] = lds_frag32(LB(cur), wn * 64 + n * 16 + fr, fq);
    #pragma unroll
    for (int m = 0; m < 4; ++m)
      #pragma unroll
      for (int n = 0; n < 4; ++n)
        acc[m][n] = MFMA(af[m], bfr[n], acc[m][n]);
    __syncthreads();
  }
#undef STAGE
#undef LA
#undef LB

  // ---- epilogue: two half-passes, f32 staged as [128][64] (32KB)
  float* fs = (float*)lds;
  const int crow = threadIdx.x >> 4;            // 0..15
  const int cq = threadIdx.x & 15;              // 16B column unit
  #pragma unroll
  for (int half = 0; half < 2; ++half) {
    #pragma unroll
    for (int n2 = 0; n2 < 2; ++n2) {
      const int n = half * 2 + n2;
      #pragma unroll
      for (int m = 0; m < 4; ++m)
        #pragma unroll
        for (int r = 0; r < 4; ++r) {
          const int row = wm * 64 + m * 16 + fq * 4 + r;
          const int cpos = wn * 32 + n2 * 16 + fr;   // 0..63 within half
          const int col = tn + wn * 64 + n * 16 + fr;
          const int byte = (row * 256 + cpos * 4) ^ ((row & 7) << 4);
          *(float*)((char*)fs + byte) = acc[m][n][r] + ldv(bias, col, f32);
        }
    }
    __syncthreads();
    #pragma unroll
    for (int pass = 0; pass < 8; ++pass) {
      const int row = pass * 16 + crow;
      const int byte = (row * 256 + cq * 16) ^ ((row & 7) << 4);
      const float4 v = *(const float4*)((const char*)fs + byte);
      const int cpos = cq * 4;                       // 0..60
      const int gcol = tn + (cpos >> 5) * 64 + half * 32 + (cpos & 31);
      const size_t g = (size_t)(b0 * 128 + tm + row) * 1024 + gcol;
      if (f32) {
        *(float4*)&((float*)out)[g] = v;
      } else {
        bf16x4 o = { (short)f2bf(v.x), (short)f2bf(v.y),
                     (short)f2bf(v.z), (short)f2bf(v.w) };
        *(bf16x4*)&((u16*)out)[g] = o;
      }
    }
    __syncthreads();  // protect stage of next half
  }
}

// ---------------------------------------------------------------------------
extern "C" void kernel_launch(void* const* d_in, const int* in_sizes, int n_in,
                              void* d_out, int out_size, void* d_ws, size_t ws_size,
                              hipStream_t stream) {
  // d_in: 0 words, 1 position, 2 conscious, 3 Wq_w, 4 Wk_w, 5 Wv_w,
  //       6 Wq_p, 7 Wk_p, 8 Wq_c, 9 Wk_c, 10 Wo, 11 bo
  // ws: [flag 64B][WT 8*1M bf16][Abf 3*CHB*128K bf16 (merged aliases Abf)]
  //     [P 7*CHB*128K bf16]
  const size_t fixed = 64ull + 8ull * 1048576ull * 2ull;
  int CHB = 128;
  while (CHB > 2 && fixed + 10ull * (size_t)CHB * 131072ull * 2ull > ws_size)
    CHB >>= 1;

  int* flag = (int*)d_ws;
  u16* WT = (u16*)((char*)d_ws + 64);
  u16* Abf = WT + 8ull * 1048576ull;
  u16* P = Abf + 3ull * (size_t)CHB * 131072ull;
  u16* merged = Abf;  // alias: Abf dead after proj, merged live attn->final

  detect_dtype<<<1, 256, 0, stream>>>(d_in[0], flag);
  cast_w<<<dim3(32, 32, 8), 256, 0, stream>>>(
      d_in[3], d_in[4], d_in[5], d_in[6], d_in[7], d_in[8], d_in[9], d_in[10],
      WT, flag);

  for (int b0 = 0; b0 < 128; b0 += CHB) {
    cast_a<<<dim3(512, 1, 3), 256, 0, stream>>>(
        d_in[0], d_in[1], d_in[2], Abf, b0, CHB, flag);
    proj_mfma<<<dim3(8, CHB, 7), 256, 0, stream>>>(Abf, WT, P, CHB);
    attn_mfma<<<dim3(8, CHB), 256, 0, stream>>>(P, CHB, merged);
    final_mfma<<<dim3(8, CHB), 256, 0, stream>>>(
        merged, WT + 7ull * 1048576ull, d_in[11], d_out, b0, flag);
  }
}